// Round 7
// baseline (242.822 us; speedup 1.0000x reference)
//
#include <hip/hip_runtime.h>

#define THREADS 512

typedef _Float16 f16x8 __attribute__((ext_vector_type(8)));
typedef float f32x4 __attribute__((ext_vector_type(4)));

#define MFMA(A, B, C) __builtin_amdgcn_mfma_f32_16x16x32_f16(A, B, C, 0, 0, 0)

struct P16 { f16x8 hi, lo; };

__device__ __forceinline__ P16 split16(float4 a, float4 b) {
  float v[8] = {a.x, a.y, a.z, a.w, b.x, b.y, b.z, b.w};
  P16 p;
#pragma unroll
  for (int e = 0; e < 8; ++e) {
    const _Float16 h = (_Float16)v[e];
    const _Float16 lw = (_Float16)(v[e] - (float)h);
    p.hi[e] = h; p.lo[e] = lw;
  }
  return p;
}

__device__ __forceinline__ float sigm(float a) {
  return __builtin_amdgcn_rcpf(1.0f + __expf(-a));
}

// W [512][28] f32 -> f16 hi/lo fragment planes: wf[{0,1}*32 + T][lane] = uint4
// element e: k = 4g+e (e<4) | 16+4g+(e-4), g=lane>>4; W-col = 16T + (lane&15)
__global__ void prep_wfrag(const float* __restrict__ W, uint4* __restrict__ wf) {
  const int id = blockIdx.x * 256 + threadIdx.x;
  if (id >= 2048) return;
  const int T = id >> 6, l = id & 63, g = (l >> 4) & 3, li = l & 15;
  const int col = 16 * T + li;
  unsigned hi[8], lo[8];
#pragma unroll
  for (int e = 0; e < 8; ++e) {
    const int k = (e < 4) ? (4 * g + e) : (16 + 4 * g + (e - 4));
    const float v = (k < 28) ? W[col * 28 + k] : 0.0f;
    const _Float16 h = (_Float16)v;
    const _Float16 lw = (_Float16)(v - (float)h);
    hi[e] = __builtin_bit_cast(unsigned short, h);
    lo[e] = __builtin_bit_cast(unsigned short, lw);
  }
  uint4 uh, ul;
  uh.x = hi[0] | (hi[1] << 16); uh.y = hi[2] | (hi[3] << 16);
  uh.z = hi[4] | (hi[5] << 16); uh.w = hi[6] | (hi[7] << 16);
  ul.x = lo[0] | (lo[1] << 16); ul.y = lo[2] | (lo[3] << 16);
  ul.z = lo[4] | (lo[5] << 16); ul.w = lo[6] | (lo[7] << 16);
  wf[T * 64 + l] = uh;
  wf[(32 + T) * 64 + l] = ul;
}

// One block = one sample; 512 threads = 8 waves.
// H~ = f16-pair(sigmoid(xW^T+b)) stored as hi/lo PLANES [32][256] f16 per chunk,
// columns k-permuted to the MFMA frag pattern + 16B-granule XOR-row swizzle:
// every G fragment = one ds_read_b128 per plane, zero unpack VALU.
// G = H~ H~^T (4-term f16 MFMA, f32 accum); Y = G^-1 x (Gauss-Jordan, wave 0);
// X = x (H full row-rank); B = H~^T Y with H~ recomputed per tile (out-frag == B-operand).
__global__ __launch_bounds__(THREADS, 6) void elm_kernel(
    const float* __restrict__ x, const uint4* __restrict__ wf,
    const float* __restrict__ bias, float* __restrict__ Xout,
    float* __restrict__ Bout)
{
  __shared__ __align__(16) unsigned short Hc16[16384]; // 32KB: hi[0,8192) lo[8192,16384); later f32 scratch + B staging
  __shared__ __align__(16) float xs[1152];  // x [32][36], zero-padded
  __shared__ __align__(16) float Yt[1152];  // Y^T [32][36], zero-padded
  __shared__ __align__(16) float Gc[896];   // G [28][32]
  // total 45568 B -> 3 blocks/CU

  const int tid = threadIdx.x;
  const int n = blockIdx.x;
  const int w = tid >> 6, l = tid & 63, gl = l >> 4, li = l & 15;
  const int tr = w >> 2, q = w & 3, tl = 2 * w;
  const float* xi = x + (size_t)n * 784;

  // ---- 0. init: zero Yt + xs pads, load x, X = x ----
  if (tid < 288) reinterpret_cast<float4*>(Yt)[tid] = float4{0, 0, 0, 0};
  if (tid < 28) {
    *reinterpret_cast<float4*>(&xs[tid * 36 + 28]) = float4{0, 0, 0, 0};
    *reinterpret_cast<float4*>(&xs[tid * 36 + 32]) = float4{0, 0, 0, 0};
  } else if (tid < 64) {
    *reinterpret_cast<float4*>(&xs[1008 + (tid - 28) * 4]) = float4{0, 0, 0, 0};
  } else if (tid < 260) {
    const int t = tid - 64;
    const float4 v = reinterpret_cast<const float4*>(xi)[t];
    reinterpret_cast<float4*>(Xout + (size_t)n * 784)[t] = v;
    const int r = t / 7, c4 = t - r * 7;
    *reinterpret_cast<float4*>(&xs[r * 36 + 4 * c4]) = v;
  }
  __syncthreads();

  // ---- 1. x A-fragments ----
  P16 X0, X1;
  {
    const float4 a0 = *reinterpret_cast<const float4*>(&xs[li * 36 + 4 * gl]);
    const float4 b0 = *reinterpret_cast<const float4*>(&xs[li * 36 + 16 + 4 * gl]);
    const float4 a1 = *reinterpret_cast<const float4*>(&xs[(16 + li) * 36 + 4 * gl]);
    const float4 b1 = *reinterpret_cast<const float4*>(&xs[(16 + li) * 36 + 16 + 4 * gl]);
    X0 = split16(a0, b0); X1 = split16(a1, b1);
  }

  // ---- 2/3. H chunks (f16 plane stores) + G accumulation (4-term, b128 frag reads) ----
  f32x4 d0 = {0, 0, 0, 0}, d1 = {0, 0, 0, 0};
  for (int c = 0; c < 2; ++c) {
#pragma unroll
    for (int j = 0; j < 2; ++j) {
      const int Tl = tl + j;        // chunk-local tile 0..15
      const int T = 16 * c + Tl;    // global tile 0..31
      const f16x8 Whi = __builtin_bit_cast(f16x8, wf[T * 64 + l]);
      const f16x8 Wlo = __builtin_bit_cast(f16x8, wf[(32 + T) * 64 + l]);
      f32x4 a0 = {0, 0, 0, 0}, a1 = {0, 0, 0, 0};
      a0 = MFMA(X0.hi, Whi, a0); a0 = MFMA(X0.hi, Wlo, a0); a0 = MFMA(X0.lo, Whi, a0);
      a1 = MFMA(X1.hi, Whi, a1); a1 = MFMA(X1.hi, Wlo, a1); a1 = MFMA(X1.lo, Whi, a1);
      const float bv = bias[16 * T + li];
      // storage position: k-step s=Tl>>1, granule = s*4 + li>>2, off = (li&3)+4*(Tl&1)
      const int gran = (Tl >> 1) * 4 + (li >> 2);
      const int off = (li & 3) + 4 * (Tl & 1);
#pragma unroll
      for (int i = 0; i < 4; ++i) {
        const int r0 = 4 * gl + i;
        const float h0 = sigm(a0[i] + bv);
        const _Float16 h0h = (_Float16)h0;
        const _Float16 h0l = (_Float16)(h0 - (float)h0h);
        const int i0 = r0 * 256 + ((gran ^ r0) << 3) + off;
        Hc16[i0] = __builtin_bit_cast(unsigned short, h0h);
        Hc16[8192 + i0] = __builtin_bit_cast(unsigned short, h0l);
        const int r1 = 16 + 4 * gl + i;
        const float h1 = (r1 < 28) ? sigm(a1[i] + bv) : 0.0f;
        const _Float16 h1h = (_Float16)h1;
        const _Float16 h1l = (_Float16)(h1 - (float)h1h);
        const int i1 = r1 * 256 + ((gran ^ r1) << 3) + off;
        Hc16[i1] = __builtin_bit_cast(unsigned short, h1h);
        Hc16[8192 + i1] = __builtin_bit_cast(unsigned short, h1l);
      }
    }
    __syncthreads();
#pragma unroll
    for (int ss = 0; ss < 2; ++ss) {
      const int s = q + 4 * ss;                  // chunk-local 32-col k-step
      const int gb = (s * 4 + gl) << 3;          // unswizzled granule byte/2 idx
      const int rA = tr * 16 + li;
      const int iA = rA * 256 + (gb ^ (rA << 3));
      const int iB0 = li * 256 + (gb ^ (li << 3));
      const int rB1 = 16 + li;
      const int iB1 = rB1 * 256 + (gb ^ (rB1 << 3));
      // note: (gran ^ row)<<3 == (gran<<3) ^ (row<<3) since gran,row < 32
      const f16x8 Ahi = *reinterpret_cast<const f16x8*>(&Hc16[iA & 8191]);
      const f16x8 Alo = *reinterpret_cast<const f16x8*>(&Hc16[8192 + (iA & 8191)]);
      const f16x8 B0hi = *reinterpret_cast<const f16x8*>(&Hc16[iB0 & 8191]);
      const f16x8 B0lo = *reinterpret_cast<const f16x8*>(&Hc16[8192 + (iB0 & 8191)]);
      const f16x8 B1hi = *reinterpret_cast<const f16x8*>(&Hc16[iB1 & 8191]);
      const f16x8 B1lo = *reinterpret_cast<const f16x8*>(&Hc16[8192 + (iB1 & 8191)]);
      d0 = MFMA(Ahi, B0hi, d0); d0 = MFMA(Ahi, B0lo, d0);
      d0 = MFMA(Alo, B0hi, d0); d0 = MFMA(Alo, B0lo, d0);
      d1 = MFMA(Ahi, B1hi, d1); d1 = MFMA(Ahi, B1lo, d1);
      d1 = MFMA(Alo, B1hi, d1); d1 = MFMA(Alo, B1lo, d1);
    }
    __syncthreads();
  }

  // ---- 4. G reduce across k-quarters (scratch in dead Hc) ----
  float* sc = reinterpret_cast<float*>(Hc16);
  if (q != 0) {
    const int idx = ((tr * 3 + (q - 1)) * 64 + l) * 8;
    *reinterpret_cast<float4*>(&sc[idx]) = float4{d0[0], d0[1], d0[2], d0[3]};
    *reinterpret_cast<float4*>(&sc[idx + 4]) = float4{d1[0], d1[1], d1[2], d1[3]};
  }
  __syncthreads();
  if (q == 0) {
#pragma unroll
    for (int p = 0; p < 3; ++p) {
      const int idx = ((tr * 3 + p) * 64 + l) * 8;
      const float4 u = *reinterpret_cast<const float4*>(&sc[idx]);
      const float4 v = *reinterpret_cast<const float4*>(&sc[idx + 4]);
      d0[0] += u.x; d0[1] += u.y; d0[2] += u.z; d0[3] += u.w;
      d1[0] += v.x; d1[1] += v.y; d1[2] += v.z; d1[3] += v.w;
    }
#pragma unroll
    for (int i = 0; i < 4; ++i) {
      const int r = tr * 16 + 4 * gl + i;
      if (r < 28) { Gc[r * 32 + li] = d0[i]; Gc[r * 32 + 16 + li] = d1[i]; }
    }
  }
  __syncthreads();

  // ---- 5. solve G Y = x : Gauss-Jordan on wave 0, lane j owns augmented col j ----
  if (tid < 64) {
    const int j = tid;
    float col[28];
#pragma unroll
    for (int r = 0; r < 28; ++r) {
      float v = 0.f;
      if (j < 28)      v = Gc[r * 32 + j];
      else if (j < 56) v = xs[r * 36 + (j - 28)];
      col[r] = v;
    }
#pragma unroll
    for (int k = 0; k < 28; ++k) {
      const float piv = __shfl(col[k], k);
      const float pivinv = 1.0f / piv;
      col[k] *= pivinv;
#pragma unroll
      for (int r2 = 0; r2 < 28; ++r2) {
        if (r2 == k) continue;
        const float m = __shfl(col[r2], k);
        col[r2] -= m * col[k];
      }
    }
    if (j >= 28 && j < 56) {
      const int c2 = j - 28;
#pragma unroll
      for (int r2 = 0; r2 < 28; ++r2) Yt[c2 * 36 + r2] = col[r2];
    }
  }
  __syncthreads();

  // ---- 6. B = H~^T Y : recompute H per tile, MFMA out-fragment == B-operand ----
  P16 Y0, Y1;
  {
    const float4 a0 = *reinterpret_cast<const float4*>(&Yt[li * 36 + 4 * gl]);
    const float4 b0 = *reinterpret_cast<const float4*>(&Yt[li * 36 + 16 + 4 * gl]);
    const float4 a1 = *reinterpret_cast<const float4*>(&Yt[(16 + li) * 36 + 4 * gl]);
    const float4 b1 = *reinterpret_cast<const float4*>(&Yt[(16 + li) * 36 + 16 + 4 * gl]);
    Y0 = split16(a0, b0); Y1 = split16(a1, b1);
  }
  float* Bs = reinterpret_cast<float*>(Hc16);
  for (int grp = 0; grp < 2; ++grp) {
#pragma unroll
    for (int j = 0; j < 2; ++j) {
      const int T = 16 * grp + tl + j;
      const f16x8 Whi = __builtin_bit_cast(f16x8, wf[T * 64 + l]);
      const f16x8 Wlo = __builtin_bit_cast(f16x8, wf[(32 + T) * 64 + l]);
      f32x4 a0 = {0, 0, 0, 0}, a1 = {0, 0, 0, 0};
      a0 = MFMA(X0.hi, Whi, a0); a0 = MFMA(X0.hi, Wlo, a0); a0 = MFMA(X0.lo, Whi, a0);
      a1 = MFMA(X1.hi, Whi, a1); a1 = MFMA(X1.hi, Wlo, a1); a1 = MFMA(X1.lo, Whi, a1);
      const float bv = bias[16 * T + li];
      f16x8 Bhi, Blo;
#pragma unroll
      for (int i = 0; i < 4; ++i) {
        const float h0 = sigm(a0[i] + bv);
        const _Float16 hh0 = (_Float16)h0;
        Bhi[i] = hh0; Blo[i] = (_Float16)(h0 - (float)hh0);
        const int r1 = 16 + 4 * gl + i;
        const float h1 = (r1 < 28) ? sigm(a1[i] + bv) : 0.0f;
        const _Float16 hh1 = (_Float16)h1;
        Bhi[4 + i] = hh1; Blo[4 + i] = (_Float16)(h1 - (float)hh1);
      }
      f32x4 bt0 = {0, 0, 0, 0}, bt1 = {0, 0, 0, 0};
      bt0 = MFMA(Y0.hi, Bhi, bt0); bt0 = MFMA(Y0.hi, Blo, bt0); bt0 = MFMA(Y0.lo, Bhi, bt0);
      bt1 = MFMA(Y1.hi, Bhi, bt1); bt1 = MFMA(Y1.hi, Blo, bt1); bt1 = MFMA(Y1.lo, Bhi, bt1);
      const int hp = 16 * (tl + j) + li;          // 0..255 within group
      *reinterpret_cast<float4*>(&Bs[hp * 28 + 4 * gl]) = float4{bt0[0], bt0[1], bt0[2], bt0[3]};
      if (gl < 3)
        *reinterpret_cast<float4*>(&Bs[hp * 28 + 16 + 4 * gl]) = float4{bt1[0], bt1[1], bt1[2], bt1[3]};
    }
    __syncthreads();
    const float4* Bs4 = reinterpret_cast<const float4*>(Bs);
    float4* Bo4 = reinterpret_cast<float4*>(Bout + (size_t)n * 14336 + grp * 7168);
#pragma unroll
    for (int k2 = 0; k2 < 4; ++k2) {
      const int idx = tid + 512 * k2;
      if (idx < 1792) Bo4[idx] = Bs4[idx];
    }
    __syncthreads();
  }
}

extern "C" void kernel_launch(void* const* d_in, const int* in_sizes, int n_in,
                              void* d_out, int out_size, void* d_ws, size_t ws_size,
                              hipStream_t stream) {
  const float* x = (const float*)d_in[0];
  const float* W = (const float*)d_in[1];
  const float* b = (const float*)d_in[2];
  const int N = in_sizes[0] / 784;               // 4096 samples
  float* Xout = (float*)d_out;                   // [N,1,28,28]
  float* Bout = Xout + (size_t)N * 784;          // [N,1,512,28]
  uint4* wf = (uint4*)d_ws;                      // 65536 B
  prep_wfrag<<<8, 256, 0, stream>>>(W, wf);
  elm_kernel<<<N, THREADS, 0, stream>>>(x, wf, b, Xout, Bout);
}

// Round 8
// 161.208 us; speedup vs baseline: 1.5063x; 1.5063x over previous
//
#include <hip/hip_runtime.h>

#define THREADS 512

typedef _Float16 f16x8 __attribute__((ext_vector_type(8)));
typedef float f32x4 __attribute__((ext_vector_type(4)));

#define MFMA(A, B, C) __builtin_amdgcn_mfma_f32_16x16x32_f16(A, B, C, 0, 0, 0)

struct P16 { f16x8 hi, lo; };

__device__ __forceinline__ P16 split16(float4 a, float4 b) {
  float v[8] = {a.x, a.y, a.z, a.w, b.x, b.y, b.z, b.w};
  P16 p;
#pragma unroll
  for (int e = 0; e < 8; ++e) {
    const _Float16 h = (_Float16)v[e];
    const _Float16 lw = (_Float16)(v[e] - (float)h);
    p.hi[e] = h; p.lo[e] = lw;
  }
  return p;
}

__device__ __forceinline__ float sigm(float a) {
  return __builtin_amdgcn_rcpf(1.0f + __expf(-a));
}

// W [512][28] f32 -> f16 hi/lo fragment planes: wf[{0,1}*32 + T][lane] = uint4
// element e: k = 4g+e (e<4) | 16+4g+(e-4), g=lane>>4; W-col = 16T + (lane&15)
__global__ void prep_wfrag(const float* __restrict__ W, uint4* __restrict__ wf) {
  const int id = blockIdx.x * 256 + threadIdx.x;
  if (id >= 2048) return;
  const int T = id >> 6, l = id & 63, g = (l >> 4) & 3, li = l & 15;
  const int col = 16 * T + li;
  unsigned hi[8], lo[8];
#pragma unroll
  for (int e = 0; e < 8; ++e) {
    const int k = (e < 4) ? (4 * g + e) : (16 + 4 * g + (e - 4));
    const float v = (k < 28) ? W[col * 28 + k] : 0.0f;
    const _Float16 h = (_Float16)v;
    const _Float16 lw = (_Float16)(v - (float)h);
    hi[e] = __builtin_bit_cast(unsigned short, h);
    lo[e] = __builtin_bit_cast(unsigned short, lw);
  }
  uint4 uh, ul;
  uh.x = hi[0] | (hi[1] << 16); uh.y = hi[2] | (hi[3] << 16);
  uh.z = hi[4] | (hi[5] << 16); uh.w = hi[6] | (hi[7] << 16);
  ul.x = lo[0] | (lo[1] << 16); ul.y = lo[2] | (lo[3] << 16);
  ul.z = lo[4] | (lo[5] << 16); ul.w = lo[6] | (lo[7] << 16);
  wf[T * 64 + l] = uh;
  wf[(32 + T) * 64 + l] = ul;
}

// One block = one sample; 512 threads = 8 waves; 2 blocks/CU (128 VGPR -> no spills).
// H~ = f16-pair(sigmoid(xW^T+b)) stored as hi/lo PLANES [32][256] f16 per chunk,
// columns k-permuted to the MFMA frag pattern + 16B-granule XOR-row swizzle:
// every G fragment = one ds_read_b128 per plane, zero unpack VALU.
// G = H~ H~^T (4-term f16 MFMA, f32 accum); Y = G^-1 x (Gauss-Jordan, wave 0);
// X = x (H full row-rank); B = H~^T Y with H~ recomputed per tile (out-frag == B-operand).
__global__ __launch_bounds__(THREADS, 4) void elm_kernel(
    const float* __restrict__ x, const uint4* __restrict__ wf,
    const float* __restrict__ bias, float* __restrict__ Xout,
    float* __restrict__ Bout)
{
  __shared__ __align__(16) unsigned short Hc16[16384]; // 32KB: hi/lo planes; later f32 scratch + B staging
  __shared__ __align__(16) float xs[1152];  // x [32][36], zero-padded
  __shared__ __align__(16) float Yt[1152];  // Y^T [32][36], zero-padded
  __shared__ __align__(16) float Gc[896];   // G [28][32]
  // total 45568 B

  const int tid = threadIdx.x;
  const int n = blockIdx.x;
  const int w = tid >> 6, l = tid & 63, gl = l >> 4, li = l & 15;
  const int tr = w >> 2, q = w & 3, tl = 2 * w;
  const float* xi = x + (size_t)n * 784;

  // ---- 0. init: zero Yt + xs pads, load x, X = x ----
  if (tid < 288) reinterpret_cast<float4*>(Yt)[tid] = float4{0, 0, 0, 0};
  if (tid < 28) {
    *reinterpret_cast<float4*>(&xs[tid * 36 + 28]) = float4{0, 0, 0, 0};
    *reinterpret_cast<float4*>(&xs[tid * 36 + 32]) = float4{0, 0, 0, 0};
  } else if (tid < 64) {
    *reinterpret_cast<float4*>(&xs[1008 + (tid - 28) * 4]) = float4{0, 0, 0, 0};
  } else if (tid < 260) {
    const int t = tid - 64;
    const float4 v = reinterpret_cast<const float4*>(xi)[t];
    reinterpret_cast<float4*>(Xout + (size_t)n * 784)[t] = v;
    const int r = t / 7, c4 = t - r * 7;
    *reinterpret_cast<float4*>(&xs[r * 36 + 4 * c4]) = v;
  }
  __syncthreads();

  // ---- 1. x A-fragments ----
  P16 X0, X1;
  {
    const float4 a0 = *reinterpret_cast<const float4*>(&xs[li * 36 + 4 * gl]);
    const float4 b0 = *reinterpret_cast<const float4*>(&xs[li * 36 + 16 + 4 * gl]);
    const float4 a1 = *reinterpret_cast<const float4*>(&xs[(16 + li) * 36 + 4 * gl]);
    const float4 b1 = *reinterpret_cast<const float4*>(&xs[(16 + li) * 36 + 16 + 4 * gl]);
    X0 = split16(a0, b0); X1 = split16(a1, b1);
  }

  // ---- 2/3. H chunks (f16 plane stores) + G accumulation (4-term, b128 frag reads) ----
  f32x4 d0 = {0, 0, 0, 0}, d1 = {0, 0, 0, 0};
  for (int c = 0; c < 2; ++c) {
#pragma unroll
    for (int j = 0; j < 2; ++j) {
      const int Tl = tl + j;        // chunk-local tile 0..15
      const int T = 16 * c + Tl;    // global tile 0..31
      const f16x8 Whi = __builtin_bit_cast(f16x8, wf[T * 64 + l]);
      const f16x8 Wlo = __builtin_bit_cast(f16x8, wf[(32 + T) * 64 + l]);
      f32x4 a0 = {0, 0, 0, 0}, a1 = {0, 0, 0, 0};
      a0 = MFMA(X0.hi, Whi, a0); a0 = MFMA(X0.hi, Wlo, a0); a0 = MFMA(X0.lo, Whi, a0);
      a1 = MFMA(X1.hi, Whi, a1); a1 = MFMA(X1.hi, Wlo, a1); a1 = MFMA(X1.lo, Whi, a1);
      const float bv = bias[16 * T + li];
      // storage position: k-step s=Tl>>1, granule = s*4 + li>>2, off = (li&3)+4*(Tl&1)
      const int gran = (Tl >> 1) * 4 + (li >> 2);
      const int off = (li & 3) + 4 * (Tl & 1);
#pragma unroll
      for (int i = 0; i < 4; ++i) {
        const int r0 = 4 * gl + i;
        const float h0 = sigm(a0[i] + bv);
        const _Float16 h0h = (_Float16)h0;
        const _Float16 h0l = (_Float16)(h0 - (float)h0h);
        const int i0 = r0 * 256 + ((gran ^ r0) << 3) + off;
        Hc16[i0] = __builtin_bit_cast(unsigned short, h0h);
        Hc16[8192 + i0] = __builtin_bit_cast(unsigned short, h0l);
        const int r1 = 16 + 4 * gl + i;
        const float h1 = (r1 < 28) ? sigm(a1[i] + bv) : 0.0f;
        const _Float16 h1h = (_Float16)h1;
        const _Float16 h1l = (_Float16)(h1 - (float)h1h);
        const int i1 = r1 * 256 + ((gran ^ r1) << 3) + off;
        Hc16[i1] = __builtin_bit_cast(unsigned short, h1h);
        Hc16[8192 + i1] = __builtin_bit_cast(unsigned short, h1l);
      }
    }
    __syncthreads();
#pragma unroll
    for (int ss = 0; ss < 2; ++ss) {
      const int s = q + 4 * ss;                  // chunk-local 32-col k-step
      const int gb = (s * 4 + gl) << 3;          // unswizzled granule idx (x8 shorts)
      const int rA = tr * 16 + li;
      const int iA = rA * 256 + (gb ^ (rA << 3));
      const int iB0 = li * 256 + (gb ^ (li << 3));
      const int rB1 = 16 + li;
      const int iB1 = rB1 * 256 + (gb ^ (rB1 << 3));
      const f16x8 Ahi = *reinterpret_cast<const f16x8*>(&Hc16[iA]);
      const f16x8 Alo = *reinterpret_cast<const f16x8*>(&Hc16[8192 + iA]);
      const f16x8 B0hi = *reinterpret_cast<const f16x8*>(&Hc16[iB0]);
      const f16x8 B0lo = *reinterpret_cast<const f16x8*>(&Hc16[8192 + iB0]);
      const f16x8 B1hi = *reinterpret_cast<const f16x8*>(&Hc16[iB1]);
      const f16x8 B1lo = *reinterpret_cast<const f16x8*>(&Hc16[8192 + iB1]);
      d0 = MFMA(Ahi, B0hi, d0); d0 = MFMA(Ahi, B0lo, d0);
      d0 = MFMA(Alo, B0hi, d0); d0 = MFMA(Alo, B0lo, d0);
      d1 = MFMA(Ahi, B1hi, d1); d1 = MFMA(Ahi, B1lo, d1);
      d1 = MFMA(Alo, B1hi, d1); d1 = MFMA(Alo, B1lo, d1);
    }
    __syncthreads();
  }

  // ---- 4. G reduce across k-quarters (scratch in dead Hc) ----
  float* sc = reinterpret_cast<float*>(Hc16);
  if (q != 0) {
    const int idx = ((tr * 3 + (q - 1)) * 64 + l) * 8;
    *reinterpret_cast<float4*>(&sc[idx]) = float4{d0[0], d0[1], d0[2], d0[3]};
    *reinterpret_cast<float4*>(&sc[idx + 4]) = float4{d1[0], d1[1], d1[2], d1[3]};
  }
  __syncthreads();
  if (q == 0) {
#pragma unroll
    for (int p = 0; p < 3; ++p) {
      const int idx = ((tr * 3 + p) * 64 + l) * 8;
      const float4 u = *reinterpret_cast<const float4*>(&sc[idx]);
      const float4 v = *reinterpret_cast<const float4*>(&sc[idx + 4]);
      d0[0] += u.x; d0[1] += u.y; d0[2] += u.z; d0[3] += u.w;
      d1[0] += v.x; d1[1] += v.y; d1[2] += v.z; d1[3] += v.w;
    }
#pragma unroll
    for (int i = 0; i < 4; ++i) {
      const int r = tr * 16 + 4 * gl + i;
      if (r < 28) { Gc[r * 32 + li] = d0[i]; Gc[r * 32 + 16 + li] = d1[i]; }
    }
  }
  __syncthreads();

  // ---- 5. solve G Y = x : Gauss-Jordan on wave 0, lane j owns augmented col j ----
  if (tid < 64) {
    const int j = tid;
    float col[28];
#pragma unroll
    for (int r = 0; r < 28; ++r) {
      float v = 0.f;
      if (j < 28)      v = Gc[r * 32 + j];
      else if (j < 56) v = xs[r * 36 + (j - 28)];
      col[r] = v;
    }
#pragma unroll
    for (int k = 0; k < 28; ++k) {
      const float piv = __shfl(col[k], k);
      const float pivinv = 1.0f / piv;
      col[k] *= pivinv;
#pragma unroll
      for (int r2 = 0; r2 < 28; ++r2) {
        if (r2 == k) continue;
        const float m = __shfl(col[r2], k);
        col[r2] -= m * col[k];
      }
    }
    if (j >= 28 && j < 56) {
      const int c2 = j - 28;
#pragma unroll
      for (int r2 = 0; r2 < 28; ++r2) Yt[c2 * 36 + r2] = col[r2];
    }
  }
  __syncthreads();

  // ---- 6. B = H~^T Y : recompute H per tile, MFMA out-fragment == B-operand ----
  P16 Y0, Y1;
  {
    const float4 a0 = *reinterpret_cast<const float4*>(&Yt[li * 36 + 4 * gl]);
    const float4 b0 = *reinterpret_cast<const float4*>(&Yt[li * 36 + 16 + 4 * gl]);
    const float4 a1 = *reinterpret_cast<const float4*>(&Yt[(16 + li) * 36 + 4 * gl]);
    const float4 b1 = *reinterpret_cast<const float4*>(&Yt[(16 + li) * 36 + 16 + 4 * gl]);
    Y0 = split16(a0, b0); Y1 = split16(a1, b1);
  }
  float* Bs = reinterpret_cast<float*>(Hc16);
  for (int grp = 0; grp < 2; ++grp) {
#pragma unroll
    for (int j = 0; j < 2; ++j) {
      const int T = 16 * grp + tl + j;
      const f16x8 Whi = __builtin_bit_cast(f16x8, wf[T * 64 + l]);
      const f16x8 Wlo = __builtin_bit_cast(f16x8, wf[(32 + T) * 64 + l]);
      f32x4 a0 = {0, 0, 0, 0}, a1 = {0, 0, 0, 0};
      a0 = MFMA(X0.hi, Whi, a0); a0 = MFMA(X0.hi, Wlo, a0); a0 = MFMA(X0.lo, Whi, a0);
      a1 = MFMA(X1.hi, Whi, a1); a1 = MFMA(X1.hi, Wlo, a1); a1 = MFMA(X1.lo, Whi, a1);
      const float bv = bias[16 * T + li];
      f16x8 Bhi, Blo;
#pragma unroll
      for (int i = 0; i < 4; ++i) {
        const float h0 = sigm(a0[i] + bv);
        const _Float16 hh0 = (_Float16)h0;
        Bhi[i] = hh0; Blo[i] = (_Float16)(h0 - (float)hh0);
        const int r1 = 16 + 4 * gl + i;
        const float h1 = (r1 < 28) ? sigm(a1[i] + bv) : 0.0f;
        const _Float16 hh1 = (_Float16)h1;
        Bhi[4 + i] = hh1; Blo[4 + i] = (_Float16)(h1 - (float)hh1);
      }
      f32x4 bt0 = {0, 0, 0, 0}, bt1 = {0, 0, 0, 0};
      bt0 = MFMA(Y0.hi, Bhi, bt0); bt0 = MFMA(Y0.hi, Blo, bt0); bt0 = MFMA(Y0.lo, Bhi, bt0);
      bt1 = MFMA(Y1.hi, Bhi, bt1); bt1 = MFMA(Y1.hi, Blo, bt1); bt1 = MFMA(Y1.lo, Bhi, bt1);
      const int hp = 16 * (tl + j) + li;          // 0..255 within group
      *reinterpret_cast<float4*>(&Bs[hp * 28 + 4 * gl]) = float4{bt0[0], bt0[1], bt0[2], bt0[3]};
      if (gl < 3)
        *reinterpret_cast<float4*>(&Bs[hp * 28 + 16 + 4 * gl]) = float4{bt1[0], bt1[1], bt1[2], bt1[3]};
    }
    __syncthreads();
    const float4* Bs4 = reinterpret_cast<const float4*>(Bs);
    float4* Bo4 = reinterpret_cast<float4*>(Bout + (size_t)n * 14336 + grp * 7168);
#pragma unroll
    for (int k2 = 0; k2 < 4; ++k2) {
      const int idx = tid + 512 * k2;
      if (idx < 1792) Bo4[idx] = Bs4[idx];
    }
    __syncthreads();
  }
}

extern "C" void kernel_launch(void* const* d_in, const int* in_sizes, int n_in,
                              void* d_out, int out_size, void* d_ws, size_t ws_size,
                              hipStream_t stream) {
  const float* x = (const float*)d_in[0];
  const float* W = (const float*)d_in[1];
  const float* b = (const float*)d_in[2];
  const int N = in_sizes[0] / 784;               // 4096 samples
  float* Xout = (float*)d_out;                   // [N,1,28,28]
  float* Bout = Xout + (size_t)N * 784;          // [N,1,512,28]
  uint4* wf = (uint4*)d_ws;                      // 65536 B
  prep_wfrag<<<8, 256, 0, stream>>>(W, wf);
  elm_kernel<<<N, THREADS, 0, stream>>>(x, wf, b, Xout, Bout);
}

// Round 10
// 116.910 us; speedup vs baseline: 2.0770x; 1.3789x over previous
//
#include <hip/hip_runtime.h>

typedef _Float16 f16x8 __attribute__((ext_vector_type(8)));
typedef _Float16 f16x4 __attribute__((ext_vector_type(4)));
typedef float f32x4 __attribute__((ext_vector_type(4)));

#define MFMA32(A, B, C) __builtin_amdgcn_mfma_f32_16x16x32_f16(A, B, C, 0, 0, 0)
#define MFMA16(A, B, C) __builtin_amdgcn_mfma_f32_16x16x16f16(A, B, C, 0, 0, 0)

struct P16 { f16x8 hi, lo; };
struct P8  { f16x4 hi, lo; };

__device__ __forceinline__ P16 split16(float4 a, float4 b) {
  float v[8] = {a.x, a.y, a.z, a.w, b.x, b.y, b.z, b.w};
  P16 p;
#pragma unroll
  for (int e = 0; e < 8; ++e) {
    const _Float16 h = (_Float16)v[e];
    p.hi[e] = h; p.lo[e] = (_Float16)(v[e] - (float)h);
  }
  return p;
}
__device__ __forceinline__ P8 split4(float a0, float a1, float a2, float a3) {
  float v[4] = {a0, a1, a2, a3};
  P8 p;
#pragma unroll
  for (int e = 0; e < 4; ++e) {
    const _Float16 h = (_Float16)v[e];
    p.hi[e] = h; p.lo[e] = (_Float16)(v[e] - (float)h);
  }
  return p;
}
__device__ __forceinline__ float sigm(float a) {
  return __builtin_amdgcn_rcpf(1.0f + __expf(-a));
}

// W [512][28] f32 -> f16 hi/lo fragment planes: wf[{0,1}*32 + T][lane] = uint4
// element e: k = 4g+e (e<4) | 16+4g+(e-4), g=lane>>4; W-col = 16T + (lane&15)
__global__ void prep_wfrag(const float* __restrict__ W, uint4* __restrict__ wf) {
  const int id = blockIdx.x * 256 + threadIdx.x;
  if (id >= 2048) return;
  const int T = id >> 6, l = id & 63, g = (l >> 4) & 3, li = l & 15;
  const int col = 16 * T + li;
  unsigned hi[8], lo[8];
#pragma unroll
  for (int e = 0; e < 8; ++e) {
    const int k = (e < 4) ? (4 * g + e) : (16 + 4 * g + (e - 4));
    const float v = (k < 28) ? W[col * 28 + k] : 0.0f;
    const _Float16 h = (_Float16)v;
    const _Float16 lw = (_Float16)(v - (float)h);
    hi[e] = __builtin_bit_cast(unsigned short, h);
    lo[e] = __builtin_bit_cast(unsigned short, lw);
  }
  uint4 uh, ul;
  uh.x = hi[0] | (hi[1] << 16); uh.y = hi[2] | (hi[3] << 16);
  uh.z = hi[4] | (hi[5] << 16); uh.w = hi[6] | (hi[7] << 16);
  ul.x = lo[0] | (lo[1] << 16); ul.y = lo[2] | (lo[3] << 16);
  ul.z = lo[4] | (lo[5] << 16); ul.w = lo[6] | (lo[7] << 16);
  wf[T * 64 + l] = uh;
  wf[(32 + T) * 64 + l] = ul;
}

// One block = one sample; 256 threads = 4 waves; target 4-5 blocks/CU.
// Wave w owns H tiles 8w..8w+7. Per tile: H C-frag -> private-LDS transpose
// (intra-wave, NO barrier) -> G += via 16x16x16 MFMA (3-term f16 hi/lo).
// G symmetric: only d00,d01,d11; mirrored at reduce. Y = G^-1 x (wave 0).
// X = x (H full row-rank). B = H^T Y, H recomputed (C-frag == B-operand frag),
// staged+flushed in two 256-row groups.
// sm words: [0,1152) xs[32][36] (later Y^T, later staging)
//           [1152,2048) Gc[28][32] (later staging)
//           [2048+w*1024 ..+1024) per-wave transpose dbuf / reduce scratch
//           staging overlays [0,7168)
__global__ __launch_bounds__(256, 4) void elm_kernel(
    const float* __restrict__ x, const uint4* __restrict__ wf,
    const float* __restrict__ bias, float* __restrict__ Xout,
    float* __restrict__ Bout)
{
  __shared__ __align__(16) float sm[7168];   // 28672 B
  const int tid = threadIdx.x, n = blockIdx.x;
  const int w = tid >> 6, l = tid & 63, gl = l >> 4, li = l & 15;
  const float* xi = x + (size_t)n * 784;

  // ---- 0. load x -> xs, X = x, zero pads ----
  if (tid < 196) {
    const float4 v = reinterpret_cast<const float4*>(xi)[tid];
    reinterpret_cast<float4*>(Xout + (size_t)n * 784)[tid] = v;
    const int r = tid / 7, c4 = tid - r * 7;
    *reinterpret_cast<float4*>(&sm[r * 36 + 4 * c4]) = v;
  }
  if (tid < 56) {                       // col pads 28..35, rows 0..27
    const int r = tid >> 1, hh = tid & 1;
    *reinterpret_cast<float4*>(&sm[r * 36 + 28 + 4 * hh]) = float4{0, 0, 0, 0};
  }
  if (tid >= 196 && tid < 232) {        // row pads 28..31 (words 1008..1151)
    *reinterpret_cast<float4*>(&sm[1008 + (tid - 196) * 4]) = float4{0, 0, 0, 0};
  }
  __syncthreads();

  // ---- 1. x A-fragments ----
  const P16 X0 = split16(*reinterpret_cast<const float4*>(&sm[li * 36 + 4 * gl]),
                         *reinterpret_cast<const float4*>(&sm[li * 36 + 16 + 4 * gl]));
  const P16 X1 = split16(*reinterpret_cast<const float4*>(&sm[(16 + li) * 36 + 4 * gl]),
                         *reinterpret_cast<const float4*>(&sm[(16 + li) * 36 + 16 + 4 * gl]));

  // ---- 2. H + intra-wave transpose + G accumulate : ZERO barriers ----
  f32x4 d00 = {0, 0, 0, 0}, d01 = {0, 0, 0, 0}, d11 = {0, 0, 0, 0};
  const int tb0 = 2048 + w * 1024;
  const int sx = li & 7;
#pragma unroll 1
  for (int t4 = 0; t4 < 8; ++t4) {
    const int T = 8 * w + t4;
    const f16x8 Whi = __builtin_bit_cast(f16x8, wf[T * 64 + l]);
    const f16x8 Wlo = __builtin_bit_cast(f16x8, wf[(32 + T) * 64 + l]);
    f32x4 a0 = {0, 0, 0, 0}, a1 = {0, 0, 0, 0};
    a0 = MFMA32(X0.hi, Whi, a0); a0 = MFMA32(X0.hi, Wlo, a0); a0 = MFMA32(X0.lo, Whi, a0);
    a1 = MFMA32(X1.hi, Whi, a1); a1 = MFMA32(X1.hi, Wlo, a1); a1 = MFMA32(X1.lo, Whi, a1);
    const float bv = bias[16 * T + li];
    float4 h0, h1;
    h0.x = sigm(a0[0] + bv); h0.y = sigm(a0[1] + bv);
    h0.z = sigm(a0[2] + bv); h0.w = sigm(a0[3] + bv);
    h1.x = (16 + 4 * gl + 0 < 28) ? sigm(a1[0] + bv) : 0.0f;
    h1.y = (16 + 4 * gl + 1 < 28) ? sigm(a1[1] + bv) : 0.0f;
    h1.z = (16 + 4 * gl + 2 < 28) ? sigm(a1[2] + bv) : 0.0f;
    h1.w = (16 + 4 * gl + 3 < 28) ? sigm(a1[3] + bv) : 0.0f;
    // transpose store: buffer [16 cols][32 rows], granule-swizzled
    const int tb = tb0 + (t4 & 1) * 512;
    *reinterpret_cast<float4*>(&sm[tb + li * 32 + ((gl ^ sx) << 2)]) = h0;
    *reinterpret_cast<float4*>(&sm[tb + li * 32 + (((4 + gl) ^ sx) << 2)]) = h1;
    // transpose read: A0 row li, A1 row 16+li, cols c = 4gl+e
    float a0e[4], a1e[4];
#pragma unroll
    for (int e = 0; e < 4; ++e) {
      const int c = 4 * gl + e;
      const int base = tb + c * 32 + (li & 3);
      a0e[e] = sm[base + ((((li >> 2)    ) ^ (c & 7)) << 2)];
      a1e[e] = sm[base + ((((li >> 2) + 4) ^ (c & 7)) << 2)];
    }
    const P8 A0 = split4(a0e[0], a0e[1], a0e[2], a0e[3]);
    const P8 A1 = split4(a1e[0], a1e[1], a1e[2], a1e[3]);
    d00 = MFMA16(A0.hi, A0.hi, d00); d00 = MFMA16(A0.hi, A0.lo, d00); d00 = MFMA16(A0.lo, A0.hi, d00);
    d01 = MFMA16(A0.hi, A1.hi, d01); d01 = MFMA16(A0.hi, A1.lo, d01); d01 = MFMA16(A0.lo, A1.hi, d01);
    d11 = MFMA16(A1.hi, A1.hi, d11); d11 = MFMA16(A1.hi, A1.lo, d11); d11 = MFMA16(A1.lo, A1.hi, d11);
  }

  // ---- 3. G reduce (waves 1-3 -> own dead transpose region), mirror, write Gc ----
  if (w != 0) {
    const int sb = tb0 + l * 12;
    *reinterpret_cast<float4*>(&sm[sb + 0]) = float4{d00[0], d00[1], d00[2], d00[3]};
    *reinterpret_cast<float4*>(&sm[sb + 4]) = float4{d01[0], d01[1], d01[2], d01[3]};
    *reinterpret_cast<float4*>(&sm[sb + 8]) = float4{d11[0], d11[1], d11[2], d11[3]};
  }
  __syncthreads();
  if (w == 0) {
#pragma unroll
    for (int p = 1; p < 4; ++p) {
      const int sb = 2048 + p * 1024 + l * 12;
      const float4 u = *reinterpret_cast<const float4*>(&sm[sb + 0]);
      const float4 v = *reinterpret_cast<const float4*>(&sm[sb + 4]);
      const float4 t = *reinterpret_cast<const float4*>(&sm[sb + 8]);
      d00[0] += u.x; d00[1] += u.y; d00[2] += u.z; d00[3] += u.w;
      d01[0] += v.x; d01[1] += v.y; d01[2] += v.z; d01[3] += v.w;
      d11[0] += t.x; d11[1] += t.y; d11[2] += t.z; d11[3] += t.w;
    }
#pragma unroll
    for (int i = 0; i < 4; ++i) {
      const int ra = 4 * gl + i;
      sm[1152 + ra * 32 + li] = d00[i];
      sm[1152 + li * 32 + ra] = d00[i];
      sm[1152 + ra * 32 + 16 + li] = d01[i];
      sm[1152 + (16 + li) * 32 + ra] = d01[i];
      sm[1152 + (16 + ra) * 32 + 16 + li] = d11[i];
      sm[1152 + (16 + li) * 32 + 16 + ra] = d11[i];
    }
    // ---- 4. solve G Y = x : Gauss-Jordan, wave 0 (no barrier: same wave) ----
    const int j = l;
    float col[28];
#pragma unroll
    for (int r = 0; r < 28; ++r) {
      float v = 0.f;
      if (j < 28)      v = sm[1152 + r * 32 + j];
      else if (j < 56) v = sm[r * 36 + (j - 28)];
      col[r] = v;
    }
#pragma unroll
    for (int k = 0; k < 28; ++k) {
      const float piv = __shfl(col[k], k);
      const float pivinv = 1.0f / piv;
      col[k] *= pivinv;
#pragma unroll
      for (int r2 = 0; r2 < 28; ++r2) {
        if (r2 == k) continue;
        const float m = __shfl(col[r2], k);
        col[r2] -= m * col[k];
      }
    }
    if (j >= 28 && j < 56) {            // Y^T into xs region: sm[c*36 + r]
      const int c2 = j - 28;
#pragma unroll
      for (int r2 = 0; r2 < 28; ++r2) sm[c2 * 36 + r2] = col[r2];
    }
  }
  __syncthreads();

  // ---- 5. Y A-fragments ----
  const P16 Y0 = split16(*reinterpret_cast<const float4*>(&sm[li * 36 + 4 * gl]),
                         *reinterpret_cast<const float4*>(&sm[li * 36 + 16 + 4 * gl]));
  const P16 Y1 = split16(*reinterpret_cast<const float4*>(&sm[(16 + li) * 36 + 4 * gl]),
                         *reinterpret_cast<const float4*>(&sm[(16 + li) * 36 + 16 + 4 * gl]));
  __syncthreads();   // all Yt reads done -> staging may overwrite everything

  // ---- 6. B = H~^T Y : recompute H per tile; stage 256 rows; flush; x2 ----
  float* Bo = Bout + (size_t)n * 14336;
#pragma unroll 1
  for (int grp = 0; grp < 2; ++grp) {
#pragma unroll 1
    for (int t4 = 0; t4 < 4; ++t4) {
      const int T = 16 * grp + 4 * w + t4;
      const f16x8 Whi = __builtin_bit_cast(f16x8, wf[T * 64 + l]);
      const f16x8 Wlo = __builtin_bit_cast(f16x8, wf[(32 + T) * 64 + l]);
      f32x4 a0 = {0, 0, 0, 0}, a1 = {0, 0, 0, 0};
      a0 = MFMA32(X0.hi, Whi, a0); a0 = MFMA32(X0.hi, Wlo, a0); a0 = MFMA32(X0.lo, Whi, a0);
      a1 = MFMA32(X1.hi, Whi, a1); a1 = MFMA32(X1.hi, Wlo, a1); a1 = MFMA32(X1.lo, Whi, a1);
      const float bv = bias[16 * T + li];
      f16x8 Bhi, Blo;
#pragma unroll
      for (int i = 0; i < 4; ++i) {
        const float h0 = sigm(a0[i] + bv);
        const _Float16 hh0 = (_Float16)h0;
        Bhi[i] = hh0; Blo[i] = (_Float16)(h0 - (float)hh0);
        const float h1 = (16 + 4 * gl + i < 28) ? sigm(a1[i] + bv) : 0.0f;
        const _Float16 hh1 = (_Float16)h1;
        Bhi[4 + i] = hh1; Blo[4 + i] = (_Float16)(h1 - (float)hh1);
      }
      f32x4 bt0 = {0, 0, 0, 0}, bt1 = {0, 0, 0, 0};
      bt0 = MFMA32(Y0.hi, Bhi, bt0); bt0 = MFMA32(Y0.hi, Blo, bt0); bt0 = MFMA32(Y0.lo, Bhi, bt0);
      bt1 = MFMA32(Y1.hi, Bhi, bt1); bt1 = MFMA32(Y1.hi, Blo, bt1); bt1 = MFMA32(Y1.lo, Bhi, bt1);
      const int hp = 16 * (4 * w + t4) + li;      // row within group: 0..255
      *reinterpret_cast<float4*>(&sm[hp * 28 + 4 * gl]) =
          float4{bt0[0], bt0[1], bt0[2], bt0[3]};
      if (gl < 3)
        *reinterpret_cast<float4*>(&sm[hp * 28 + 16 + 4 * gl]) =
            float4{bt1[0], bt1[1], bt1[2], bt1[3]};
    }
    __syncthreads();
    const float4* Bs4 = reinterpret_cast<const float4*>(sm);
    float4* Bo4 = reinterpret_cast<float4*>(Bo + grp * 7168);
#pragma unroll
    for (int k2 = 0; k2 < 7; ++k2) Bo4[k2 * 256 + tid] = Bs4[k2 * 256 + tid];
    __syncthreads();
  }
}

extern "C" void kernel_launch(void* const* d_in, const int* in_sizes, int n_in,
                              void* d_out, int out_size, void* d_ws, size_t ws_size,
                              hipStream_t stream) {
  const float* x = (const float*)d_in[0];
  const float* W = (const float*)d_in[1];
  const float* b = (const float*)d_in[2];
  const int N = in_sizes[0] / 784;               // 4096 samples
  float* Xout = (float*)d_out;                   // [N,1,28,28]
  float* Bout = Xout + (size_t)N * 784;          // [N,1,512,28]
  uint4* wf = (uint4*)d_ws;                      // 65536 B
  prep_wfrag<<<8, 256, 0, stream>>>(W, wf);
  elm_kernel<<<N, 256, 0, stream>>>(x, wf, b, Xout, Bout);
}